// Round 6
// baseline (244.958 us; speedup 1.0000x reference)
//
#include <hip/hip_runtime.h>

typedef __bf16 bf16;
typedef __bf16 bf16x8 __attribute__((ext_vector_type(8)));
typedef __bf16 bf16x4 __attribute__((ext_vector_type(4)));
typedef float f32x4 __attribute__((ext_vector_type(4)));

#define VOCAB 32000
#define HID 512
#define BATCH 128
#define SEQ 64

__device__ inline bf16x4 cvt4(float4 a) {
  bf16x4 r;
  r[0] = (bf16)a.x; r[1] = (bf16)a.y; r[2] = (bf16)a.z; r[3] = (bf16)a.w;
  return r;
}

__device__ inline float fast_tanh(float x) {
  x = fminf(fmaxf(x, -15.f), 15.f);
  float e = __expf(2.f * x);
  return (e - 1.f) / (e + 1.f);
}
__device__ inline float fast_sig(float x) {
  return 1.f / (1.f + __expf(-x));
}

// ---------------------------------------------------------------------------
// Kernel 1: pack attn_W (512x1024 fp32) -> bf16 MFMA-B-operand order.
//   One float4 (16 B contiguous) per thread: 131072 threads.
//   row = g>>8 (256 float4 per 1024-float row)  [R5 bug: used >>7 -> OOB]
// ---------------------------------------------------------------------------
__global__ __launch_bounds__(512) void k_pack(
    const float* __restrict__ attn_W, bf16* __restrict__ Wp) {
  int g = blockIdx.x * 512 + threadIdx.x;  // 0..131071
  int hh = g >> 8;                         // row h (0..511)
  int q = g & 255;                         // float4 index within row (0..255)
  float4 v = ((const float4*)(attn_W + (size_t)hh * 1024))[q];
  int c8 = q >> 1, odd = q & 1;            // 8-group of k (0..127), half
  int kchunk = c8 >> 2, klane = c8 & 3;    // kchunk 0..31
  int ntile = hh >> 4, nlane = hh & 15;
  int lane = klane * 16 + nlane;
  *(bf16x4*)(Wp + ((size_t)(kchunk * 32 + ntile) * 64 + lane) * 8 + odd * 4) =
      cvt4(v);
}

// ---------------------------------------------------------------------------
// Kernel 2: per-batch fused attention (e1 folded in as K=1024 GEMM).
//   All global reads: 16 B/lane contiguous (16 full lines / instruction).
// ---------------------------------------------------------------------------
__global__ __launch_bounds__(512) void k_attn(
    const float* __restrict__ enc, const bf16* __restrict__ Wp,
    const float* __restrict__ attn_b, const float* __restrict__ vvec,
    const float* __restrict__ emb, const int* __restrict__ ids,
    const float* __restrict__ h0, bf16* __restrict__ Acat,
    float* __restrict__ gates_ws) {
  __shared__ char smem[65536];
  __shared__ bf16 h0s[512];
  bf16* encA = (bf16*)smem;                 // phase 1: 64x512 bf16 (swizzled)
  float* spart = (float*)smem;              // phase 2: 8x64
  float* wgt = (float*)(smem + 2048);       // 64
  float* ctxp = (float*)(smem + 2304);      // 4x512 fp32 partial context

  int b = blockIdx.x, tid = threadIdx.x;
  int w = tid >> 6, lane = tid & 63;
  int l15 = lane & 15, lq = lane >> 4;
  const float* encb = enc + (size_t)b * SEQ * HID;

  // zero the gates accumulator
  {
    int gid = b * 512 + tid;
    float4 z = {0.f, 0.f, 0.f, 0.f};
    ((float4*)gates_ws)[gid] = z;
  }

  h0s[tid] = (bf16)h0[b * 512 + tid];

  // stage enc[b] -> bf16 LDS: thread (r=tid>>3, sub=tid&7), 16 iters of
  // one float4 each; per instruction: 8 rows x 128 B contiguous = 16 lines.
  {
    int r = tid >> 3, sub = tid & 7;
    const float* src = encb + (size_t)r * 512;
#pragma unroll
    for (int i = 0; i < 16; ++i) {
      int k0 = i * 32 + sub * 4;
      float4 v = *(const float4*)(src + k0);
      int c8 = i * 4 + (sub >> 1);
      int phys = c8 ^ (r & 7);
      *(bf16x4*)(encA + r * 512 + phys * 8 + (sub & 1) * 4) = cvt4(v);
    }
  }
  __syncthreads();

  f32x4 acc[4][4];
  f32x4 acc_e1[4];
#pragma unroll
  for (int mt = 0; mt < 4; ++mt)
#pragma unroll
    for (int jn = 0; jn < 4; ++jn) acc[mt][jn] = (f32x4)0.f;
#pragma unroll
  for (int jn = 0; jn < 4; ++jn) acc_e1[jn] = (f32x4)0.f;

  // h0 half: kchunks 0..15 (attn_W cols 0..511), row-invariant accumulator
#pragma unroll 4
  for (int kc = 0; kc < 16; ++kc) {
    bf16x8 af = *(const bf16x8*)(h0s + kc * 32 + lq * 8);
#pragma unroll
    for (int jn = 0; jn < 4; ++jn) {
      int nt = w * 4 + jn;
      bf16x8 bfr = *(const bf16x8*)(Wp + ((size_t)(kc * 32 + nt) * 64 + lane) * 8);
      acc_e1[jn] = __builtin_amdgcn_mfma_f32_16x16x32_bf16(af, bfr, acc_e1[jn], 0, 0, 0);
    }
  }

  // enc half: kchunks 16..31 (attn_W cols 512..1023)
#pragma unroll 2
  for (int kc = 16; kc < 32; ++kc) {
    bf16x8 bfr[4], af[4];
#pragma unroll
    for (int jn = 0; jn < 4; ++jn) {
      int nt = w * 4 + jn;
      bfr[jn] = *(const bf16x8*)(Wp + ((size_t)(kc * 32 + nt) * 64 + lane) * 8);
    }
#pragma unroll
    for (int mt = 0; mt < 4; ++mt) {
      int row = mt * 16 + l15;
      int c = (kc - 16) * 4 + lq;
      int phys = c ^ (row & 7);
      af[mt] = *(const bf16x8*)(encA + row * 512 + phys * 8);
    }
#pragma unroll
    for (int mt = 0; mt < 4; ++mt)
#pragma unroll
      for (int jn = 0; jn < 4; ++jn)
        acc[mt][jn] = __builtin_amdgcn_mfma_f32_16x16x32_bf16(
            af[mt], bfr[jn], acc[mt][jn], 0, 0, 0);
  }
  __syncthreads();  // encA dead; smem reused

  // epilogue: scores
  float p[4][4];
#pragma unroll
  for (int mt = 0; mt < 4; ++mt)
#pragma unroll
    for (int r = 0; r < 4; ++r) p[mt][r] = 0.f;
#pragma unroll
  for (int jn = 0; jn < 4; ++jn) {
    int h = (w * 4 + jn) * 16 + l15;
    float bias = attn_b[h];
    float vv = vvec[h];
#pragma unroll
    for (int mt = 0; mt < 4; ++mt)
#pragma unroll
      for (int r = 0; r < 4; ++r)
        p[mt][r] += vv * fast_tanh(acc[mt][jn][r] + acc_e1[jn][r] + bias);
  }
#pragma unroll
  for (int mt = 0; mt < 4; ++mt)
#pragma unroll
    for (int r = 0; r < 4; ++r) {
      float x = p[mt][r];
      x += __shfl_xor(x, 1);
      x += __shfl_xor(x, 2);
      x += __shfl_xor(x, 4);
      x += __shfl_xor(x, 8);
      p[mt][r] = x;
    }
  if (l15 == 0) {
#pragma unroll
    for (int mt = 0; mt < 4; ++mt)
#pragma unroll
      for (int r = 0; r < 4; ++r) {
        int s = mt * 16 + lq * 4 + r;
        spart[w * 64 + s] = p[mt][r];
      }
  }
  __syncthreads();

  // softmax over s (wave 0)
  if (tid < 64) {
    float sc = 0.f;
#pragma unroll
    for (int ww = 0; ww < 8; ++ww) sc += spart[ww * 64 + tid];
    float mx = sc;
    for (int m = 32; m; m >>= 1) mx = fmaxf(mx, __shfl_xor(mx, m));
    float e = __expf(sc - mx);
    float sm = e;
    for (int m = 32; m; m >>= 1) sm += __shfl_xor(sm, m);
    wgt[tid] = e / sm;
  }
  __syncthreads();

  // context: thread (sg=tid>>7 over 4 s-groups of 16, hc2=tid&127 float4 col)
  // per instruction: 64 lanes x 16 B contiguous = 16 full lines (L2-hot).
  {
    int sg = tid >> 7, hc2 = tid & 127;
    float a4[4] = {0.f, 0.f, 0.f, 0.f};
    for (int s = sg * 16; s < sg * 16 + 16; ++s) {
      float wv = wgt[s];
      float4 x = ((const float4*)(encb + (size_t)s * 512))[hc2];
      a4[0] += wv * x.x; a4[1] += wv * x.y; a4[2] += wv * x.z; a4[3] += wv * x.w;
    }
#pragma unroll
    for (int j = 0; j < 4; ++j) ctxp[sg * 512 + hc2 * 4 + j] = a4[j];
  }
  __syncthreads();

  {
    int h = tid;
    float c = 0.f;
#pragma unroll
    for (int g = 0; g < 4; ++g) c += ctxp[g * 512 + h];
    int id = ids[b];
    Acat[(size_t)b * 1536 + h] = (bf16)emb[(size_t)id * 512 + h];
    Acat[(size_t)b * 1536 + 512 + h] = (bf16)c;
    Acat[(size_t)b * 1536 + 1024 + h] = (bf16)h0[b * 512 + h];
  }
}

// ---------------------------------------------------------------------------
// Kernel 3: gates partial GEMM, single barrier. grid (32 n-tiles, 6 ks).
//   Staging: thread (r=tid>>3, sub=tid&7), 8 x one-float4 loads
//   (8 rows x 128 B contiguous = 16 full lines per instruction).
// ---------------------------------------------------------------------------
__global__ __launch_bounds__(512) void k_gates(
    const bf16* __restrict__ Acat, const float* __restrict__ W_ih,
    const float* __restrict__ W_hh, float* __restrict__ gates_ws) {
  int nb = blockIdx.x, ks = blockIdx.y;
  __shared__ bf16 Wl[64 * 256];  // 32 KB
  int tid = threadIdx.x, w = tid >> 6, lane = tid & 63;
  int l15 = lane & 15, lq = lane >> 4;
  int wm = w >> 1, wn = w & 1;

  {
    int r = tid >> 3, sub = tid & 7;
    int grow = nb * 64 + r;
    const float* src = (ks < 4) ? (W_ih + (size_t)grow * 1024 + ks * 256)
                                : (W_hh + (size_t)grow * 512 + (ks - 4) * 256);
#pragma unroll
    for (int i = 0; i < 8; ++i) {
      int k0 = i * 32 + sub * 4;
      float4 v = *(const float4*)(src + k0);
      int c8 = i * 4 + (sub >> 1);
      int phys = c8 ^ (r & 7);
      *(bf16x4*)(Wl + r * 256 + phys * 8 + (sub & 1) * 4) = cvt4(v);
    }
  }
  __syncthreads();

  f32x4 acc[2][2];
#pragma unroll
  for (int i = 0; i < 2; ++i)
#pragma unroll
    for (int j = 0; j < 2; ++j) acc[i][j] = (f32x4)0.f;

#pragma unroll 4
  for (int kt = 0; kt < 8; ++kt) {
    int ko = ks * 256 + kt * 32 + lq * 8;
    bf16x8 bfr[2], af[2];
#pragma unroll
    for (int jn = 0; jn < 2; ++jn) {
      int row = (wn * 2 + jn) * 16 + l15;
      int c = kt * 4 + lq;
      int phys = c ^ (row & 7);
      bfr[jn] = *(const bf16x8*)(Wl + row * 256 + phys * 8);
    }
#pragma unroll
    for (int mi = 0; mi < 2; ++mi) {
      int m = (wm * 2 + mi) * 16 + l15;
      af[mi] = *(const bf16x8*)(Acat + (size_t)m * 1536 + ko);
    }
#pragma unroll
    for (int mi = 0; mi < 2; ++mi)
#pragma unroll
      for (int jn = 0; jn < 2; ++jn)
        acc[mi][jn] = __builtin_amdgcn_mfma_f32_16x16x32_bf16(
            af[mi], bfr[jn], acc[mi][jn], 0, 0, 0);
  }
#pragma unroll
  for (int mi = 0; mi < 2; ++mi)
#pragma unroll
    for (int jn = 0; jn < 2; ++jn)
#pragma unroll
      for (int rr = 0; rr < 4; ++rr) {
        int bb = (wm * 2 + mi) * 16 + lq * 4 + rr;
        int n = nb * 64 + (wn * 2 + jn) * 16 + l15;
        atomicAdd(&gates_ws[(size_t)bb * 2048 + n], acc[mi][jn][rr]);
      }
}

// ---------------------------------------------------------------------------
// Kernel 4: elementwise LSTM cell.
// ---------------------------------------------------------------------------
__global__ __launch_bounds__(512) void k_cell(
    const float* __restrict__ gates_ws, const float* __restrict__ b_ih,
    const float* __restrict__ b_hh, const float* __restrict__ c0,
    float* __restrict__ out, bf16* __restrict__ hnewb) {
  int idx = blockIdx.x * 512 + threadIdx.x;  // 0..65535
  int b = idx >> 9, h = idx & 511;
  const float* g = gates_ws + (size_t)b * 2048;
  float iv = g[h] + b_ih[h] + b_hh[h];
  float fv = g[512 + h] + b_ih[512 + h] + b_hh[512 + h];
  float gv = g[1024 + h] + b_ih[1024 + h] + b_hh[1024 + h];
  float ov = g[1536 + h] + b_ih[1536 + h] + b_hh[1536 + h];
  float cn = fast_sig(fv) * c0[idx] + fast_sig(iv) * fast_tanh(gv);
  float hn = fast_sig(ov) * fast_tanh(cn);
  out[4096000 + idx] = hn;
  out[4096000 + 65536 + idx] = cn;
  hnewb[idx] = (bf16)hn;
}

// ---------------------------------------------------------------------------
// Kernel 5: FC, single barrier. 1000 blocks x 32 vocab rows.
//   Staging: thread (r=tid>>4, sub=tid&15), 8 x one-float4 loads
//   (4 rows x 256 B contiguous = 16 full 64 B lines per instruction);
//   bf16x4 LDS writes, XOR-swizzled. Then barrier-free MFMA phase.
// ---------------------------------------------------------------------------
__global__ __launch_bounds__(512) void k_fc(
    const bf16* __restrict__ hnewb, const float* __restrict__ fc_W,
    const float* __restrict__ fc_b, float* __restrict__ out) {
  int vb = blockIdx.x * 32;
  __shared__ bf16 Wl[32 * 512];  // 32 KB
  int tid = threadIdx.x, w = tid >> 6, lane = tid & 63;
  int l15 = lane & 15, lq = lane >> 4;
  int wm = w >> 1, wn = w & 1;

  {
    int r = tid >> 4, sub = tid & 15;
    const float* src = fc_W + (size_t)(vb + r) * 512;
#pragma unroll
    for (int i = 0; i < 8; ++i) {
      int k0 = i * 64 + sub * 4;
      float4 v = *(const float4*)(src + k0);
      int c8 = i * 8 + (sub >> 1);
      int phys = c8 ^ (r & 7);
      *(bf16x4*)(Wl + r * 512 + phys * 8 + (sub & 1) * 4) = cvt4(v);
    }
  }
  __syncthreads();

  f32x4 acc[2];
  acc[0] = (f32x4)0.f;
  acc[1] = (f32x4)0.f;

  const bf16* a0 = hnewb + (size_t)((wm * 2 + 0) * 16 + l15) * 512 + lq * 8;
  const bf16* a1 = hnewb + (size_t)((wm * 2 + 1) * 16 + l15) * 512 + lq * 8;
  int browbase = wn * 16 + l15;

#pragma unroll 4
  for (int kt = 0; kt < 16; ++kt) {
    int c = kt * 4 + lq;
    int phys = c ^ (browbase & 7);
    bf16x8 bfr = *(const bf16x8*)(Wl + browbase * 512 + phys * 8);
    bf16x8 af0 = *(const bf16x8*)(a0 + kt * 32);
    bf16x8 af1 = *(const bf16x8*)(a1 + kt * 32);
    acc[0] = __builtin_amdgcn_mfma_f32_16x16x32_bf16(af0, bfr, acc[0], 0, 0, 0);
    acc[1] = __builtin_amdgcn_mfma_f32_16x16x32_bf16(af1, bfr, acc[1], 0, 0, 0);
  }

  int vv = vb + wn * 16 + l15;
  float bias = fc_b[vv];
#pragma unroll
  for (int mi = 0; mi < 2; ++mi)
#pragma unroll
    for (int rr = 0; rr < 4; ++rr) {
      int bb = (wm * 2 + mi) * 16 + lq * 4 + rr;
      out[(size_t)bb * 32000 + vv] = acc[mi][rr] + bias;
    }
}

extern "C" void kernel_launch(void* const* d_in, const int* in_sizes, int n_in,
                              void* d_out, int out_size, void* d_ws,
                              size_t ws_size, hipStream_t stream) {
  const int* ids = (const int*)d_in[0];
  const float* h0 = (const float*)d_in[1];
  const float* c0 = (const float*)d_in[2];
  const float* enc = (const float*)d_in[3];
  const float* emb = (const float*)d_in[4];
  const float* attn_W = (const float*)d_in[5];
  const float* attn_b = (const float*)d_in[6];
  const float* vvec = (const float*)d_in[7];
  const float* W_ih = (const float*)d_in[8];
  const float* W_hh = (const float*)d_in[9];
  const float* b_ih = (const float*)d_in[10];
  const float* b_hh = (const float*)d_in[11];
  const float* fc_W = (const float*)d_in[12];
  const float* fc_b = (const float*)d_in[13];
  float* out = (float*)d_out;
  char* ws = (char*)d_ws;

  bf16* Wp = (bf16*)ws;                     // 512*1024*2    = 1048576
  bf16* Acat = (bf16*)(ws + 1048576);       // 128*1536*2    = 393216
  bf16* hnewb = (bf16*)(ws + 1441792);      // 128*512*2     = 131072
  float* gates = (float*)(ws + 1572864);    // 128*2048*4    = 1048576

  k_pack<<<256, 512, 0, stream>>>(attn_W, Wp);
  k_attn<<<128, 512, 0, stream>>>(enc, Wp, attn_b, vvec, emb, ids, h0, Acat, gates);
  k_gates<<<dim3(32, 6), 512, 0, stream>>>(Acat, W_ih, W_hh, gates);
  k_cell<<<128, 512, 0, stream>>>(gates, b_ih, b_hh, c0, out, hnewb);
  k_fc<<<1000, 512, 0, stream>>>(hnewb, fc_W, fc_b, out);
}